// Round 2
// baseline (936.146 us; speedup 1.0000x reference)
//
#include <hip/hip_runtime.h>
#include <hip/hip_cooperative_groups.h>
#include <math.h>

namespace cg = cooperative_groups;

#define N0 1000000
#define N1 40960
#define N2 4096
#define E1 1024000
#define E2 40960
#define IN_C 100
#define HID 256
#define OUT_C 47
#define S1 128   // ELL stride layer1 (deg ~Poisson(25))
#define S2 64    // ELL stride layer2 (deg ~Poisson(10))
#define KCAT 224          // padded K for [agg|x] (200 -> 224 = 7*32)
#define KSTEPS 7          // 224/32
#define LDSTR 232         // LDS row stride in bf16 (padded: 464B, bank-safe)

#define GRID_C 1024       // cooperative grid: 4 blocks/CU @ 256 thr, VGPR<=128
#define GSTRIDE (GRID_C * 256)

typedef __attribute__((ext_vector_type(8))) short short8;
typedef __attribute__((ext_vector_type(4))) float float4v;

// fp32 -> bf16 RNE (finite inputs)
__device__ inline unsigned short f2bf(float f) {
    union { float f; unsigned u; } v; v.f = f;
    unsigned r = v.u + 0x7FFF + ((v.u >> 16) & 1);
    return (unsigned short)(r >> 16);
}

// ===========================================================================
// Cooperative mega-kernel: P1 build (ELL + W-pack) | grid.sync |
// P2 fused agg+GEMM1 | grid.sync | P3 fused layer-2.
// Bodies are bit-identical to the 3-kernel version (fallback below).
// ===========================================================================
__global__ __launch_bounds__(256, 4) void mega_kernel(
    const float* __restrict__ x,
    const int* __restrict__ src1, const int* __restrict__ dst1,
    const int* __restrict__ src2, const int* __restrict__ dst2,
    int* __restrict__ deg1, int* __restrict__ ell1,
    int* __restrict__ deg2, int* __restrict__ ell2,
    const float* __restrict__ W1l, const float* __restrict__ W1r,
    const float* __restrict__ b1l,
    const float* __restrict__ W2l, const float* __restrict__ b2l,
    const float* __restrict__ W2r,
    unsigned short* __restrict__ packedW,
    float* __restrict__ h, float* __restrict__ out) {
    __shared__ short As[32 * LDSTR];   // 14,848 B (P2)
    __shared__ float sa[4][HID];       // 4 KB (P3)
    __shared__ float sh_[4][HID];      // 4 KB (P3)

    cg::grid_group grid = cg::this_grid();
    int tid = threadIdx.x;
    int bid = blockIdx.x;
    int gtid = bid * 256 + tid;
    int lane = tid & 63;
    int w = tid >> 6;

    // ---------------- P1: W-pack + ELL build ----------------
    if (gtid < 7168) {
        int nt = gtid / 448;
        int rem = gtid - nt * 448;
        int ks = rem >> 6;
        int pl = rem & 63;
        int n = nt * 16 + (pl & 15);
        int kbase = ks * 32 + (pl >> 4) * 8;
        unsigned short* wp = packedW + (size_t)(nt * 7 + ks) * 512 + pl * 8;
        #pragma unroll
        for (int j = 0; j < 8; ++j) {
            int k = kbase + j;
            float v = (k < 100) ? W1l[k * HID + n]
                    : (k < 200) ? W1r[(k - 100) * HID + n] : 0.f;
            wp[j] = f2bf(v);
        }
    }
    for (int u = gtid; u < E1 / 2 + E2 / 2; u += GSTRIDE) {
        if (u < E1 / 2) {
            int2 s = ((const int2*)src1)[u];
            int2 d = ((const int2*)dst1)[u];
            int slot0 = atomicAdd(&deg1[d.x], 1);
            if (slot0 < S1) ell1[d.x * S1 + slot0] = s.x;
            int slot1 = atomicAdd(&deg1[d.y], 1);
            if (slot1 < S1) ell1[d.y * S1 + slot1] = s.y;
        } else {
            int p = u - E1 / 2;
            int2 s = ((const int2*)src2)[p];
            int2 d = ((const int2*)dst2)[p];
            int slot0 = atomicAdd(&deg2[d.x], 1);
            if (slot0 < S2) ell2[d.x * S2 + slot0] = s.x;
            int slot1 = atomicAdd(&deg2[d.y], 1);
            if (slot1 < S2) ell2[d.y * S2 + slot1] = s.y;
        }
    }
    grid.sync();

    // ---------------- P2: fused agg + GEMM1 (grid-stride over 1280 tiles) ---
    for (int t = bid; t < N1 / 32; t += GRID_C) {
        int i0 = t * 32;

        // stage x_self -> k[100..199]
        const float2* xs2 = (const float2*)(x + (size_t)i0 * IN_C);
        for (int idx = tid; idx < 32 * 50; idx += 256) {
            int r = idx / 50;
            int p = idx - r * 50;
            float2 v = xs2[idx];
            short2 o = {(short)f2bf(v.x), (short)f2bf(v.y)};
            *(short2*)(As + r * LDSTR + 100 + 2 * p) = o;
        }
        // zero pad k[200..223]
        for (int idx = tid; idx < 32 * 12; idx += 256) {
            int r = idx / 12;
            int p = idx - r * 12;
            short2 z = {0, 0};
            *(short2*)(As + r * LDSTR + 200 + 2 * p) = z;
        }

        // aggregation: wave w owns rows w*8..w*8+7 of the A-tile
        int l2 = (lane < 50) ? lane : 49;
        for (int rr = 0; rr < 8; ++rr) {
            int d = i0 + w * 8 + rr;
            int nd = deg1[d];
            int n = (nd < S1) ? nd : S1;
            const int* rp = ell1 + d * S1;

            float x0 = 0.f, y0 = 0.f, x1 = 0.f, y1 = 0.f;
            float x2 = 0.f, y2 = 0.f, x3 = 0.f, y3 = 0.f;
            int e = 0;
            for (; e + 7 < n; e += 8) {
                int s0 = rp[e],     s1 = rp[e + 1], s2 = rp[e + 2], s3 = rp[e + 3];
                int s4 = rp[e + 4], s5 = rp[e + 5], s6 = rp[e + 6], s7 = rp[e + 7];
                float2 v0 = ((const float2*)(x + s0 * IN_C))[l2];
                float2 v1 = ((const float2*)(x + s1 * IN_C))[l2];
                float2 v2 = ((const float2*)(x + s2 * IN_C))[l2];
                float2 v3 = ((const float2*)(x + s3 * IN_C))[l2];
                float2 v4 = ((const float2*)(x + s4 * IN_C))[l2];
                float2 v5 = ((const float2*)(x + s5 * IN_C))[l2];
                float2 v6 = ((const float2*)(x + s6 * IN_C))[l2];
                float2 v7 = ((const float2*)(x + s7 * IN_C))[l2];
                x0 += v0.x + v4.x; y0 += v0.y + v4.y;
                x1 += v1.x + v5.x; y1 += v1.y + v5.y;
                x2 += v2.x + v6.x; y2 += v2.y + v6.y;
                x3 += v3.x + v7.x; y3 += v3.y + v7.y;
            }
            for (; e + 1 < n; e += 2) {
                int s0 = rp[e], s1 = rp[e + 1];
                float2 v0 = ((const float2*)(x + s0 * IN_C))[l2];
                float2 v1 = ((const float2*)(x + s1 * IN_C))[l2];
                x0 += v0.x; y0 += v0.y;
                x1 += v1.x; y1 += v1.y;
            }
            if (e < n) {
                float2 v0 = ((const float2*)(x + rp[e] * IN_C))[l2];
                x0 += v0.x; y0 += v0.y;
            }
            float sx = (x0 + x1) + (x2 + x3);
            float sy = (y0 + y1) + (y2 + y3);
            float inv = 1.0f / (float)(nd > 0 ? nd : 1);
            if (lane < 50) {
                short2 o = {(short)f2bf(sx * inv), (short)f2bf(sy * inv)};
                *(short2*)(As + (w * 8 + rr) * LDSTR + 2 * lane) = o;
            }
        }
        __syncthreads();

        int quad = lane >> 4;
        int m = lane & 15;

        float4v acc[2][4];
        #pragma unroll
        for (int rt = 0; rt < 2; ++rt)
            #pragma unroll
            for (int c = 0; c < 4; ++c) acc[rt][c] = (float4v){0.f, 0.f, 0.f, 0.f};

        #pragma unroll
        for (int ks = 0; ks < KSTEPS; ++ks) {
            int ko = ks * 32 + quad * 8;
            short8 a0 = *(const short8*)(As + (0 * 16 + m) * LDSTR + ko);
            short8 a1 = *(const short8*)(As + (1 * 16 + m) * LDSTR + ko);
            #pragma unroll
            for (int c = 0; c < 4; ++c) {
                int nt = w * 4 + c;
                short8 b = *(const short8*)(packedW + (size_t)(nt * 7 + ks) * 512 + lane * 8);
                acc[0][c] = __builtin_amdgcn_mfma_f32_16x16x32_bf16(a0, b, acc[0][c], 0, 0, 0);
                acc[1][c] = __builtin_amdgcn_mfma_f32_16x16x32_bf16(a1, b, acc[1][c], 0, 0, 0);
            }
        }

        #pragma unroll
        for (int c = 0; c < 4; ++c) {
            int col = (w * 4 + c) * 16 + m;
            float bv = b1l[col];
            #pragma unroll
            for (int rt = 0; rt < 2; ++rt) {
                int rbase = i0 + rt * 16 + quad * 4;
                #pragma unroll
                for (int reg = 0; reg < 4; ++reg) {
                    float v = acc[rt][c][reg] + bv;
                    h[(size_t)(rbase + reg) * HID + col] = fmaxf(v, 0.f);
                }
            }
        }
        __syncthreads();   // protect As before next tile re-stages
    }
    grid.sync();

    // ---------------- P3: fused layer-2 (1024 blocks x 4 rows exactly) -----
    {
        int row = (bid << 2) + w;
        int nd = deg2[row];
        int n = (nd < S2) ? nd : S2;
        const int* rp = ell2 + row * S2;
        float4 acc4 = {0.f, 0.f, 0.f, 0.f};
        int e = 0;
        for (; e + 1 < n; e += 2) {
            int s0 = rp[e], s1 = rp[e + 1];
            float4 v0 = ((const float4*)(h + s0 * HID))[lane];
            float4 v1 = ((const float4*)(h + s1 * HID))[lane];
            acc4.x += v0.x + v1.x; acc4.y += v0.y + v1.y;
            acc4.z += v0.z + v1.z; acc4.w += v0.w + v1.w;
        }
        if (e < n) {
            int s0 = rp[e];
            float4 v0 = ((const float4*)(h + s0 * HID))[lane];
            acc4.x += v0.x; acc4.y += v0.y; acc4.z += v0.z; acc4.w += v0.w;
        }
        float inv = 1.0f / (float)(nd > 0 ? nd : 1);
        float4 am = {acc4.x * inv, acc4.y * inv, acc4.z * inv, acc4.w * inv};
        ((float4*)&sa[w][0])[lane] = am;
        ((float4*)&sh_[w][0])[lane] = ((const float4*)(h + row * HID))[lane];
        __syncthreads();

        int j = lane;
        int jj = (j < OUT_C) ? j : (OUT_C - 1);
        float acc = 0.f;
        for (int k = 0; k < HID; k += 4) {
            float4 av = *(const float4*)&sa[w][k];   // same-addr broadcast
            float4 hv = *(const float4*)&sh_[w][k];
            acc += av.x * W2l[(k + 0) * OUT_C + jj] + hv.x * W2r[(k + 0) * OUT_C + jj];
            acc += av.y * W2l[(k + 1) * OUT_C + jj] + hv.y * W2r[(k + 1) * OUT_C + jj];
            acc += av.z * W2l[(k + 2) * OUT_C + jj] + hv.z * W2r[(k + 2) * OUT_C + jj];
            acc += av.w * W2l[(k + 3) * OUT_C + jj] + hv.w * W2r[(k + 3) * OUT_C + jj];
        }
        float v = acc + b2l[jj];
        float vm = (j < OUT_C) ? v : -__builtin_huge_valf();
        #pragma unroll
        for (int s = 32; s > 0; s >>= 1) vm = fmaxf(vm, __shfl_xor(vm, s));
        float ex = (j < OUT_C) ? __expf(v - vm) : 0.f;
        #pragma unroll
        for (int s = 32; s > 0; s >>= 1) ex += __shfl_xor(ex, s);
        if (j < OUT_C) out[row * OUT_C + j] = v - vm - __logf(ex);
    }
}

// ===========================================================================
// Fallback path: proven 3-kernel pipeline (identical numerics).
// ===========================================================================
#define EDGE_BLKS ((E1 / 2 + E2 / 2) / 256)   // 2080
#define PACK_BLKS 28
__global__ __launch_bounds__(256) void build_kernel(
    const int* __restrict__ src1, const int* __restrict__ dst1,
    const int* __restrict__ src2, const int* __restrict__ dst2,
    int* __restrict__ deg1, int* __restrict__ ell1,
    int* __restrict__ deg2, int* __restrict__ ell2,
    const float* __restrict__ W1l, const float* __restrict__ W1r,
    unsigned short* __restrict__ packedW) {
    if (blockIdx.x >= EDGE_BLKS) {
        int t = (blockIdx.x - EDGE_BLKS) * 256 + threadIdx.x;
        int nt = t / 448;
        int rem = t - nt * 448;
        int ks = rem >> 6;
        int lane = rem & 63;
        int n = nt * 16 + (lane & 15);
        int kbase = ks * 32 + (lane >> 4) * 8;
        unsigned short* wp = packedW + (size_t)(nt * 7 + ks) * 512 + lane * 8;
        #pragma unroll
        for (int j = 0; j < 8; ++j) {
            int k = kbase + j;
            float v = (k < 100) ? W1l[k * HID + n]
                    : (k < 200) ? W1r[(k - 100) * HID + n] : 0.f;
            wp[j] = f2bf(v);
        }
        return;
    }
    int gid = blockIdx.x * 256 + threadIdx.x;
    if (gid < E1 / 2) {
        int2 s = ((const int2*)src1)[gid];
        int2 d = ((const int2*)dst1)[gid];
        int slot0 = atomicAdd(&deg1[d.x], 1);
        if (slot0 < S1) ell1[d.x * S1 + slot0] = s.x;
        int slot1 = atomicAdd(&deg1[d.y], 1);
        if (slot1 < S1) ell1[d.y * S1 + slot1] = s.y;
    } else {
        int p = gid - E1 / 2;
        int2 s = ((const int2*)src2)[p];
        int2 d = ((const int2*)dst2)[p];
        int slot0 = atomicAdd(&deg2[d.x], 1);
        if (slot0 < S2) ell2[d.x * S2 + slot0] = s.x;
        int slot1 = atomicAdd(&deg2[d.y], 1);
        if (slot1 < S2) ell2[d.y * S2 + slot1] = s.y;
    }
}

__global__ __launch_bounds__(256) void agg_gemm1_kernel(
    const float* __restrict__ x, const int* __restrict__ ell1,
    const int* __restrict__ deg1,
    const unsigned short* __restrict__ packedW, const float* __restrict__ b1l,
    float* __restrict__ h) {
    __shared__ short As[32 * LDSTR];
    int tid = threadIdx.x;
    int i0 = blockIdx.x * 32;
    int lane = tid & 63;
    int w = tid >> 6;

    const float2* xs2 = (const float2*)(x + (size_t)i0 * IN_C);
    for (int idx = tid; idx < 32 * 50; idx += 256) {
        int r = idx / 50;
        int p = idx - r * 50;
        float2 v = xs2[idx];
        short2 o = {(short)f2bf(v.x), (short)f2bf(v.y)};
        *(short2*)(As + r * LDSTR + 100 + 2 * p) = o;
    }
    for (int idx = tid; idx < 32 * 12; idx += 256) {
        int r = idx / 12;
        int p = idx - r * 12;
        short2 z = {0, 0};
        *(short2*)(As + r * LDSTR + 200 + 2 * p) = z;
    }

    int l2 = (lane < 50) ? lane : 49;
    for (int rr = 0; rr < 8; ++rr) {
        int d = i0 + w * 8 + rr;
        int nd = deg1[d];
        int n = (nd < S1) ? nd : S1;
        const int* rp = ell1 + d * S1;

        float x0 = 0.f, y0 = 0.f, x1 = 0.f, y1 = 0.f;
        float x2 = 0.f, y2 = 0.f, x3 = 0.f, y3 = 0.f;
        int e = 0;
        for (; e + 7 < n; e += 8) {
            int s0 = rp[e],     s1 = rp[e + 1], s2 = rp[e + 2], s3 = rp[e + 3];
            int s4 = rp[e + 4], s5 = rp[e + 5], s6 = rp[e + 6], s7 = rp[e + 7];
            float2 v0 = ((const float2*)(x + s0 * IN_C))[l2];
            float2 v1 = ((const float2*)(x + s1 * IN_C))[l2];
            float2 v2 = ((const float2*)(x + s2 * IN_C))[l2];
            float2 v3 = ((const float2*)(x + s3 * IN_C))[l2];
            float2 v4 = ((const float2*)(x + s4 * IN_C))[l2];
            float2 v5 = ((const float2*)(x + s5 * IN_C))[l2];
            float2 v6 = ((const float2*)(x + s6 * IN_C))[l2];
            float2 v7 = ((const float2*)(x + s7 * IN_C))[l2];
            x0 += v0.x + v4.x; y0 += v0.y + v4.y;
            x1 += v1.x + v5.x; y1 += v1.y + v5.y;
            x2 += v2.x + v6.x; y2 += v2.y + v6.y;
            x3 += v3.x + v7.x; y3 += v3.y + v7.y;
        }
        for (; e + 1 < n; e += 2) {
            int s0 = rp[e], s1 = rp[e + 1];
            float2 v0 = ((const float2*)(x + s0 * IN_C))[l2];
            float2 v1 = ((const float2*)(x + s1 * IN_C))[l2];
            x0 += v0.x; y0 += v0.y;
            x1 += v1.x; y1 += v1.y;
        }
        if (e < n) {
            float2 v0 = ((const float2*)(x + rp[e] * IN_C))[l2];
            x0 += v0.x; y0 += v0.y;
        }
        float sx = (x0 + x1) + (x2 + x3);
        float sy = (y0 + y1) + (y2 + y3);
        float inv = 1.0f / (float)(nd > 0 ? nd : 1);
        if (lane < 50) {
            short2 o = {(short)f2bf(sx * inv), (short)f2bf(sy * inv)};
            *(short2*)(As + (w * 8 + rr) * LDSTR + 2 * lane) = o;
        }
    }
    __syncthreads();

    int quad = lane >> 4;
    int m = lane & 15;

    float4v acc[2][4];
    #pragma unroll
    for (int rt = 0; rt < 2; ++rt)
        #pragma unroll
        for (int c = 0; c < 4; ++c) acc[rt][c] = (float4v){0.f, 0.f, 0.f, 0.f};

    #pragma unroll
    for (int ks = 0; ks < KSTEPS; ++ks) {
        int ko = ks * 32 + quad * 8;
        short8 a0 = *(const short8*)(As + (0 * 16 + m) * LDSTR + ko);
        short8 a1 = *(const short8*)(As + (1 * 16 + m) * LDSTR + ko);
        #pragma unroll
        for (int c = 0; c < 4; ++c) {
            int nt = w * 4 + c;
            short8 b = *(const short8*)(packedW + (size_t)(nt * 7 + ks) * 512 + lane * 8);
            acc[0][c] = __builtin_amdgcn_mfma_f32_16x16x32_bf16(a0, b, acc[0][c], 0, 0, 0);
            acc[1][c] = __builtin_amdgcn_mfma_f32_16x16x32_bf16(a1, b, acc[1][c], 0, 0, 0);
        }
    }

    #pragma unroll
    for (int c = 0; c < 4; ++c) {
        int col = (w * 4 + c) * 16 + m;
        float bv = b1l[col];
        #pragma unroll
        for (int rt = 0; rt < 2; ++rt) {
            int rbase = i0 + rt * 16 + quad * 4;
            #pragma unroll
            for (int reg = 0; reg < 4; ++reg) {
                float v = acc[rt][c][reg] + bv;
                h[(size_t)(rbase + reg) * HID + col] = fmaxf(v, 0.f);
            }
        }
    }
}

__global__ __launch_bounds__(256) void l2_fused_kernel(
    const float* __restrict__ h, const int* __restrict__ ell2,
    const int* __restrict__ deg2,
    const float* __restrict__ W2l, const float* __restrict__ b2l,
    const float* __restrict__ W2r, float* __restrict__ out) {
    __shared__ float sa[4][HID];
    __shared__ float sh_[4][HID];
    int w = threadIdx.x >> 6;
    int lane = threadIdx.x & 63;
    int row = (blockIdx.x << 2) + w;

    int nd = deg2[row];
    int n = (nd < S2) ? nd : S2;
    const int* rp = ell2 + row * S2;
    float4 acc4 = {0.f, 0.f, 0.f, 0.f};
    int e = 0;
    for (; e + 1 < n; e += 2) {
        int s0 = rp[e], s1 = rp[e + 1];
        float4 v0 = ((const float4*)(h + s0 * HID))[lane];
        float4 v1 = ((const float4*)(h + s1 * HID))[lane];
        acc4.x += v0.x + v1.x; acc4.y += v0.y + v1.y;
        acc4.z += v0.z + v1.z; acc4.w += v0.w + v1.w;
    }
    if (e < n) {
        int s0 = rp[e];
        float4 v0 = ((const float4*)(h + s0 * HID))[lane];
        acc4.x += v0.x; acc4.y += v0.y; acc4.z += v0.z; acc4.w += v0.w;
    }
    float inv = 1.0f / (float)(nd > 0 ? nd : 1);
    float4 am = {acc4.x * inv, acc4.y * inv, acc4.z * inv, acc4.w * inv};
    ((float4*)&sa[w][0])[lane] = am;
    ((float4*)&sh_[w][0])[lane] = ((const float4*)(h + row * HID))[lane];
    __syncthreads();

    int j = lane;
    int jj = (j < OUT_C) ? j : (OUT_C - 1);
    float acc = 0.f;
    for (int k = 0; k < HID; k += 4) {
        float4 av = *(const float4*)&sa[w][k];
        float4 hv = *(const float4*)&sh_[w][k];
        acc += av.x * W2l[(k + 0) * OUT_C + jj] + hv.x * W2r[(k + 0) * OUT_C + jj];
        acc += av.y * W2l[(k + 1) * OUT_C + jj] + hv.y * W2r[(k + 1) * OUT_C + jj];
        acc += av.z * W2l[(k + 2) * OUT_C + jj] + hv.z * W2r[(k + 2) * OUT_C + jj];
        acc += av.w * W2l[(k + 3) * OUT_C + jj] + hv.w * W2r[(k + 3) * OUT_C + jj];
    }
    float v = acc + b2l[jj];
    float vm = (j < OUT_C) ? v : -__builtin_huge_valf();
    #pragma unroll
    for (int s = 32; s > 0; s >>= 1) vm = fmaxf(vm, __shfl_xor(vm, s));
    float ex = (j < OUT_C) ? __expf(v - vm) : 0.f;
    #pragma unroll
    for (int s = 32; s > 0; s >>= 1) ex += __shfl_xor(ex, s);
    if (j < OUT_C) out[row * OUT_C + j] = v - vm - __logf(ex);
}

// ---------------------------------------------------------------------------
extern "C" void kernel_launch(void* const* d_in, const int* in_sizes, int n_in,
                              void* d_out, int out_size, void* d_ws, size_t ws_size,
                              hipStream_t stream) {
    const float* x   = (const float*)d_in[0];
    const float* W1l = (const float*)d_in[1];
    const float* b1l = (const float*)d_in[2];
    const float* W1r = (const float*)d_in[3];
    const float* W2l = (const float*)d_in[4];
    const float* b2l = (const float*)d_in[5];
    const float* W2r = (const float*)d_in[6];
    const int* src1  = (const int*)d_in[7];
    const int* dst1  = (const int*)d_in[8];
    const int* src2  = (const int*)d_in[9];
    const int* dst2  = (const int*)d_in[10];
    float* out = (float*)d_out;

    char* ws = (char*)d_ws;
    size_t off = 0;
    auto alloc = [&](size_t bytes) {
        off = (off + 255) & ~(size_t)255;
        void* p = ws + off;
        off += bytes;
        return p;
    };

    int* deg1 = (int*)alloc(N1 * sizeof(int));       // contiguous with deg2
    int* deg2 = (int*)alloc(N2 * sizeof(int));
    int* ell1 = (int*)alloc((size_t)N1 * S1 * sizeof(int));
    int* ell2 = (int*)alloc((size_t)N2 * S2 * sizeof(int));
    float* h     = (float*)alloc((size_t)N1 * HID * sizeof(float));
    unsigned short* packedW = (unsigned short*)alloc((size_t)16 * 7 * 512 * sizeof(unsigned short));

    hipMemsetAsync(deg1, 0, (N1 + N2) * sizeof(int), stream);

    void* args[] = {
        (void*)&x, (void*)&src1, (void*)&dst1, (void*)&src2, (void*)&dst2,
        (void*)&deg1, (void*)&ell1, (void*)&deg2, (void*)&ell2,
        (void*)&W1l, (void*)&W1r, (void*)&b1l,
        (void*)&W2l, (void*)&b2l, (void*)&W2r,
        (void*)&packedW, (void*)&h, (void*)&out};
    hipError_t err = hipLaunchCooperativeKernel(
        (const void*)mega_kernel, dim3(GRID_C), dim3(256), args, 0, stream);
    if (err != hipSuccess) {
        // fallback: proven 3-kernel pipeline
        build_kernel<<<EDGE_BLKS + PACK_BLKS, 256, 0, stream>>>(
            src1, dst1, src2, dst2, deg1, ell1, deg2, ell2, W1l, W1r, packedW);
        agg_gemm1_kernel<<<N1 / 32, 256, 0, stream>>>(x, ell1, deg1, packedW, b1l, h);
        l2_fused_kernel<<<N2 / 4, 256, 0, stream>>>(h, ell2, deg2, W2l, b2l, W2r, out);
    }
}

// Round 3
// 676.922 us; speedup vs baseline: 1.3829x; 1.3829x over previous
//
#include <hip/hip_runtime.h>
#include <math.h>

#define N0 1000000
#define N1 40960
#define N2 4096
#define E1 1024000
#define E2 40960
#define IN_C 100
#define HID 256
#define OUT_C 47
#define S1 128   // ELL stride layer1 (deg ~Poisson(25))
#define S2 64    // ELL stride layer2 (deg ~Poisson(10))
#define KCAT 224          // padded K for [agg|x] (200 -> 224 = 7*32)
#define KSTEPS 7          // 224/32
#define LDSTR 232         // LDS row stride in bf16 (padded: 464B, bank-safe)

typedef __attribute__((ext_vector_type(8))) short short8;
typedef __attribute__((ext_vector_type(4))) float float4v;

// fp32 -> bf16 RNE (finite inputs)
__device__ inline unsigned short f2bf(float f) {
    union { float f; unsigned u; } v; v.f = f;
    unsigned r = v.u + 0x7FFF + ((v.u >> 16) & 1);
    return (unsigned short)(r >> 16);
}

// ---------------------------------------------------------------------------
// Single-pass ELL build (2 edges/thread, int2) + W-pack (blocks >= EDGE_BLKS).
// packed[(nt*7+ks)*512 + lane*8 + j] = bf16( Wcat[ks*32 + (lane>>4)*8 + j][nt*16 + (lane&15)] )
// Wcat[k][n] = k<100 ? W1l[k][n] : k<200 ? W1r[k-100][n] : 0
// ---------------------------------------------------------------------------
#define EDGE_BLKS ((E1 / 2 + E2 / 2) / 256)   // 2080
#define PACK_BLKS 28                          // 7168 threads, 16*7*64 chunks
__global__ __launch_bounds__(256) void build_kernel(
    const int* __restrict__ src1, const int* __restrict__ dst1,
    const int* __restrict__ src2, const int* __restrict__ dst2,
    int* __restrict__ deg1, int* __restrict__ ell1,
    int* __restrict__ deg2, int* __restrict__ ell2,
    const float* __restrict__ W1l, const float* __restrict__ W1r,
    unsigned short* __restrict__ packedW) {
    if (blockIdx.x >= EDGE_BLKS) {
        int t = (blockIdx.x - EDGE_BLKS) * 256 + threadIdx.x;  // < 7168
        int nt = t / 448;
        int rem = t - nt * 448;
        int ks = rem >> 6;
        int lane = rem & 63;
        int n = nt * 16 + (lane & 15);
        int kbase = ks * 32 + (lane >> 4) * 8;
        unsigned short* wp = packedW + (size_t)(nt * 7 + ks) * 512 + lane * 8;
        #pragma unroll
        for (int j = 0; j < 8; ++j) {
            int k = kbase + j;
            float v = (k < 100) ? W1l[k * HID + n]
                    : (k < 200) ? W1r[(k - 100) * HID + n] : 0.f;
            wp[j] = f2bf(v);
        }
        return;
    }
    int gid = blockIdx.x * 256 + threadIdx.x;
    if (gid < E1 / 2) {
        int2 s = ((const int2*)src1)[gid];
        int2 d = ((const int2*)dst1)[gid];
        int slot0 = atomicAdd(&deg1[d.x], 1);
        if (slot0 < S1) ell1[d.x * S1 + slot0] = s.x;
        int slot1 = atomicAdd(&deg1[d.y], 1);
        if (slot1 < S1) ell1[d.y * S1 + slot1] = s.y;
    } else {
        int p = gid - E1 / 2;
        int2 s = ((const int2*)src2)[p];
        int2 d = ((const int2*)dst2)[p];
        int slot0 = atomicAdd(&deg2[d.x], 1);
        if (slot0 < S2) ell2[d.x * S2 + slot0] = s.x;
        int slot1 = atomicAdd(&deg2[d.y], 1);
        if (slot1 < S2) ell2[d.y * S2 + slot1] = s.y;
    }
}

// ---------------------------------------------------------------------------
// Fused layer-1: mean-aggregation (gather) + GEMM in one kernel.
// Block = 32 dst rows. Wave w owns rows w*8..w*8+7, processed as 4 PAIRS in
// lockstep: per 8-edge batch, 16 gathers (8 per row) are in flight before any
// consumption -> 2x MLP, half the serial latency chains of the 1-row version.
// Batches are full-width with wave-uniform masks (garbage ELL slots clamped
// to row 0, contribution zeroed) -> no tail chains.
// Then bf16 MFMA: h = relu([agg|x] . [W1l;W1r] + b1l).
// mfma_f32_16x16x32_bf16: A[m=lane&15][k=quad*8+j]; D: col=lane&15, row=quad*4+reg.
// ---------------------------------------------------------------------------
__global__ __launch_bounds__(256, 4) void agg_gemm1_kernel(
    const float* __restrict__ x, const int* __restrict__ ell1,
    const int* __restrict__ deg1,
    const unsigned short* __restrict__ packedW, const float* __restrict__ b1l,
    float* __restrict__ h) {
    __shared__ short As[32 * LDSTR];   // 14,848 B
    int tid = threadIdx.x;
    int i0 = blockIdx.x * 32;
    int lane = tid & 63;
    int w = tid >> 6;

    // stage x_self -> k[100..199]
    const float2* xs2 = (const float2*)(x + (size_t)i0 * IN_C);
    for (int idx = tid; idx < 32 * 50; idx += 256) {
        int r = idx / 50;
        int p = idx - r * 50;
        float2 v = xs2[idx];
        short2 o = {(short)f2bf(v.x), (short)f2bf(v.y)};
        *(short2*)(As + r * LDSTR + 100 + 2 * p) = o;
    }
    // zero pad k[200..223]
    for (int idx = tid; idx < 32 * 12; idx += 256) {
        int r = idx / 12;
        int p = idx - r * 12;
        short2 z = {0, 0};
        *(short2*)(As + r * LDSTR + 200 + 2 * p) = z;
    }

    // aggregation: 4 row-pairs per wave, 16 gathers in flight per batch
    int l2 = (lane < 50) ? lane : 49;
    #pragma unroll 1
    for (int pr = 0; pr < 4; ++pr) {
        int dA = i0 + w * 8 + pr * 2;
        int dB = dA + 1;
        int ndA = deg1[dA], ndB = deg1[dB];
        int nA = (ndA < S1) ? ndA : S1;
        int nB = (ndB < S1) ? ndB : S1;
        const int* rpA = ell1 + dA * S1;
        const int* rpB = ell1 + dB * S1;
        float Ax0 = 0.f, Ay0 = 0.f, Ax1 = 0.f, Ay1 = 0.f;
        float Bx0 = 0.f, By0 = 0.f, Bx1 = 0.f, By1 = 0.f;
        int nmax = (nA > nB) ? nA : nB;
        for (int e = 0; e < nmax; e += 8) {   // e <= 120, e+7 < S1 always
            float2 va[8], vb[8];
            #pragma unroll
            for (int j = 0; j < 8; ++j) {
                int s = rpA[e + j];
                s = ((unsigned)s >= (unsigned)N0) ? 0 : s;   // clamp garbage slots
                va[j] = ((const float2*)(x + (size_t)s * IN_C))[l2];
            }
            #pragma unroll
            for (int j = 0; j < 8; ++j) {
                int s = rpB[e + j];
                s = ((unsigned)s >= (unsigned)N0) ? 0 : s;
                vb[j] = ((const float2*)(x + (size_t)s * IN_C))[l2];
            }
            #pragma unroll
            for (int j = 0; j < 8; ++j) {
                float mA = (e + j < nA) ? 1.f : 0.f;
                float mB = (e + j < nB) ? 1.f : 0.f;
                if (j & 1) {
                    Ax1 += va[j].x * mA; Ay1 += va[j].y * mA;
                    Bx1 += vb[j].x * mB; By1 += vb[j].y * mB;
                } else {
                    Ax0 += va[j].x * mA; Ay0 += va[j].y * mA;
                    Bx0 += vb[j].x * mB; By0 += vb[j].y * mB;
                }
            }
        }
        float invA = 1.0f / (float)(ndA > 0 ? ndA : 1);
        float invB = 1.0f / (float)(ndB > 0 ? ndB : 1);
        if (lane < 50) {
            short2 oA = {(short)f2bf((Ax0 + Ax1) * invA), (short)f2bf((Ay0 + Ay1) * invA)};
            *(short2*)(As + (w * 8 + pr * 2) * LDSTR + 2 * lane) = oA;
            short2 oB = {(short)f2bf((Bx0 + Bx1) * invB), (short)f2bf((By0 + By1) * invB)};
            *(short2*)(As + (w * 8 + pr * 2 + 1) * LDSTR + 2 * lane) = oB;
        }
    }
    __syncthreads();

    int quad = lane >> 4;
    int m = lane & 15;

    float4v acc[2][4];
    #pragma unroll
    for (int rt = 0; rt < 2; ++rt)
        #pragma unroll
        for (int c = 0; c < 4; ++c) acc[rt][c] = (float4v){0.f, 0.f, 0.f, 0.f};

    #pragma unroll
    for (int ks = 0; ks < KSTEPS; ++ks) {
        int ko = ks * 32 + quad * 8;
        short8 a0 = *(const short8*)(As + (0 * 16 + m) * LDSTR + ko);
        short8 a1 = *(const short8*)(As + (1 * 16 + m) * LDSTR + ko);
        #pragma unroll
        for (int c = 0; c < 4; ++c) {
            int nt = w * 4 + c;
            short8 b = *(const short8*)(packedW + (size_t)(nt * 7 + ks) * 512 + lane * 8);
            acc[0][c] = __builtin_amdgcn_mfma_f32_16x16x32_bf16(a0, b, acc[0][c], 0, 0, 0);
            acc[1][c] = __builtin_amdgcn_mfma_f32_16x16x32_bf16(a1, b, acc[1][c], 0, 0, 0);
        }
    }

    // epilogue: bias + relu, D layout col=lane&15 row=quad*4+reg
    #pragma unroll
    for (int c = 0; c < 4; ++c) {
        int col = (w * 4 + c) * 16 + m;
        float bv = b1l[col];
        #pragma unroll
        for (int rt = 0; rt < 2; ++rt) {
            int rbase = i0 + rt * 16 + quad * 4;
            #pragma unroll
            for (int reg = 0; reg < 4; ++reg) {
                float v = acc[rt][c][reg] + bv;
                h[(size_t)(rbase + reg) * HID + col] = fmaxf(v, 0.f);
            }
        }
    }
}

// ---------------------------------------------------------------------------
// Fused layer 2: per-wave aggregation (float4/lane over 256ch) -> LDS ->
// GEMM (lanes 0..46 = output cols) + bias + wave-level log_softmax.
// ---------------------------------------------------------------------------
__global__ __launch_bounds__(256) void l2_fused_kernel(
    const float* __restrict__ h, const int* __restrict__ ell2,
    const int* __restrict__ deg2,
    const float* __restrict__ W2l, const float* __restrict__ b2l,
    const float* __restrict__ W2r, float* __restrict__ out) {
    __shared__ float sa[4][HID];
    __shared__ float sh_[4][HID];
    int w = threadIdx.x >> 6;
    int lane = threadIdx.x & 63;
    int row = (blockIdx.x << 2) + w;

    int nd = deg2[row];
    int n = (nd < S2) ? nd : S2;
    const int* rp = ell2 + row * S2;
    float4 acc4 = {0.f, 0.f, 0.f, 0.f};
    int e = 0;
    for (; e + 1 < n; e += 2) {
        int s0 = rp[e], s1 = rp[e + 1];
        float4 v0 = ((const float4*)(h + s0 * HID))[lane];
        float4 v1 = ((const float4*)(h + s1 * HID))[lane];
        acc4.x += v0.x + v1.x; acc4.y += v0.y + v1.y;
        acc4.z += v0.z + v1.z; acc4.w += v0.w + v1.w;
    }
    if (e < n) {
        int s0 = rp[e];
        float4 v0 = ((const float4*)(h + s0 * HID))[lane];
        acc4.x += v0.x; acc4.y += v0.y; acc4.z += v0.z; acc4.w += v0.w;
    }
    float inv = 1.0f / (float)(nd > 0 ? nd : 1);
    float4 am = {acc4.x * inv, acc4.y * inv, acc4.z * inv, acc4.w * inv};
    ((float4*)&sa[w][0])[lane] = am;
    ((float4*)&sh_[w][0])[lane] = ((const float4*)(h + row * HID))[lane];
    __syncthreads();

    int j = lane;
    int jj = (j < OUT_C) ? j : (OUT_C - 1);
    float acc = 0.f;
    for (int k = 0; k < HID; k += 4) {
        float4 av = *(const float4*)&sa[w][k];   // same-addr broadcast
        float4 hv = *(const float4*)&sh_[w][k];
        acc += av.x * W2l[(k + 0) * OUT_C + jj] + hv.x * W2r[(k + 0) * OUT_C + jj];
        acc += av.y * W2l[(k + 1) * OUT_C + jj] + hv.y * W2r[(k + 1) * OUT_C + jj];
        acc += av.z * W2l[(k + 2) * OUT_C + jj] + hv.z * W2r[(k + 2) * OUT_C + jj];
        acc += av.w * W2l[(k + 3) * OUT_C + jj] + hv.w * W2r[(k + 3) * OUT_C + jj];
    }
    float v = acc + b2l[jj];
    float vm = (j < OUT_C) ? v : -__builtin_huge_valf();
    #pragma unroll
    for (int s = 32; s > 0; s >>= 1) vm = fmaxf(vm, __shfl_xor(vm, s));
    float ex = (j < OUT_C) ? __expf(v - vm) : 0.f;
    #pragma unroll
    for (int s = 32; s > 0; s >>= 1) ex += __shfl_xor(ex, s);
    if (j < OUT_C) out[row * OUT_C + j] = v - vm - __logf(ex);
}

// ---------------------------------------------------------------------------
extern "C" void kernel_launch(void* const* d_in, const int* in_sizes, int n_in,
                              void* d_out, int out_size, void* d_ws, size_t ws_size,
                              hipStream_t stream) {
    const float* x   = (const float*)d_in[0];
    const float* W1l = (const float*)d_in[1];
    const float* b1l = (const float*)d_in[2];
    const float* W1r = (const float*)d_in[3];
    const float* W2l = (const float*)d_in[4];
    const float* b2l = (const float*)d_in[5];
    const float* W2r = (const float*)d_in[6];
    const int* src1  = (const int*)d_in[7];
    const int* dst1  = (const int*)d_in[8];
    const int* src2  = (const int*)d_in[9];
    const int* dst2  = (const int*)d_in[10];
    float* out = (float*)d_out;

    char* ws = (char*)d_ws;
    size_t off = 0;
    auto alloc = [&](size_t bytes) {
        off = (off + 255) & ~(size_t)255;
        void* p = ws + off;
        off += bytes;
        return p;
    };

    int* deg1 = (int*)alloc(N1 * sizeof(int));       // contiguous with deg2
    int* deg2 = (int*)alloc(N2 * sizeof(int));
    int* ell1 = (int*)alloc((size_t)N1 * S1 * sizeof(int));
    int* ell2 = (int*)alloc((size_t)N2 * S2 * sizeof(int));
    float* h     = (float*)alloc((size_t)N1 * HID * sizeof(float));
    unsigned short* packedW = (unsigned short*)alloc((size_t)16 * 7 * 512 * sizeof(unsigned short));

    hipMemsetAsync(deg1, 0, (N1 + N2) * sizeof(int), stream);

    build_kernel<<<EDGE_BLKS + PACK_BLKS, 256, 0, stream>>>(
        src1, dst1, src2, dst2, deg1, ell1, deg2, ell2, W1l, W1r, packedW);
    agg_gemm1_kernel<<<N1 / 32, 256, 0, stream>>>(x, ell1, deg1, packedW, b1l, h);
    l2_fused_kernel<<<N2 / 4, 256, 0, stream>>>(h, ell2, deg2, W2l, b2l, W2r, out);
}

// Round 5
// 673.781 us; speedup vs baseline: 1.3894x; 1.0047x over previous
//
#include <hip/hip_runtime.h>
#include <math.h>

#define N0 1000000
#define N1 40960
#define N2 4096
#define E1 1024000
#define E2 40960
#define IN_C 100
#define HID 256
#define OUT_C 47
#define S1 128   // ELL stride layer1 (deg ~Poisson(25))
#define S2 64    // ELL stride layer2 (deg ~Poisson(10))
#define KCAT 224          // padded K for [agg|x] (200 -> 224 = 7*32)
#define KSTEPS 7          // 224/32
#define LDSTR 232         // LDS row stride in bf16 (padded: 464B, bank-safe)

typedef __attribute__((ext_vector_type(8))) short short8;
typedef __attribute__((ext_vector_type(4))) float float4v;

// fp32 -> bf16 RNE (finite inputs)
__device__ inline unsigned short f2bf(float f) {
    union { float f; unsigned u; } v; v.f = f;
    unsigned r = v.u + 0x7FFF + ((v.u >> 16) & 1);
    return (unsigned short)(r >> 16);
}

// ---------------------------------------------------------------------------
// Single-pass ELL build (4 edges/thread, int4: 4 independent atomic chains)
// + W-pack (blocks >= EDGE_BLKS).
// packed[(nt*7+ks)*512 + lane*8 + j] = bf16( Wcat[ks*32 + (lane>>4)*8 + j][nt*16 + (lane&15)] )
// Wcat[k][n] = k<100 ? W1l[k][n] : k<200 ? W1r[k-100][n] : 0
// ---------------------------------------------------------------------------
#define EDGE_BLKS ((E1 / 4 + E2 / 4) / 256)   // 1040
#define PACK_BLKS 28                          // 7168 threads, 16*7*64 chunks
__global__ __launch_bounds__(256) void build_kernel(
    const int* __restrict__ src1, const int* __restrict__ dst1,
    const int* __restrict__ src2, const int* __restrict__ dst2,
    int* __restrict__ deg1, int* __restrict__ ell1,
    int* __restrict__ deg2, int* __restrict__ ell2,
    const float* __restrict__ W1l, const float* __restrict__ W1r,
    unsigned short* __restrict__ packedW) {
    if (blockIdx.x >= EDGE_BLKS) {
        int t = (blockIdx.x - EDGE_BLKS) * 256 + threadIdx.x;  // < 7168
        int nt = t / 448;
        int rem = t - nt * 448;
        int ks = rem >> 6;
        int lane = rem & 63;
        int n = nt * 16 + (lane & 15);
        int kbase = ks * 32 + (lane >> 4) * 8;
        unsigned short* wp = packedW + (size_t)(nt * 7 + ks) * 512 + lane * 8;
        #pragma unroll
        for (int j = 0; j < 8; ++j) {
            int k = kbase + j;
            float v = (k < 100) ? W1l[k * HID + n]
                    : (k < 200) ? W1r[(k - 100) * HID + n] : 0.f;
            wp[j] = f2bf(v);
        }
        return;
    }
    int gid = blockIdx.x * 256 + threadIdx.x;
    if (gid < E1 / 4) {
        int4 s = ((const int4*)src1)[gid];
        int4 d = ((const int4*)dst1)[gid];
        int a0 = atomicAdd(&deg1[d.x], 1);
        int a1 = atomicAdd(&deg1[d.y], 1);
        int a2 = atomicAdd(&deg1[d.z], 1);
        int a3 = atomicAdd(&deg1[d.w], 1);
        if (a0 < S1) ell1[d.x * S1 + a0] = s.x;
        if (a1 < S1) ell1[d.y * S1 + a1] = s.y;
        if (a2 < S1) ell1[d.z * S1 + a2] = s.z;
        if (a3 < S1) ell1[d.w * S1 + a3] = s.w;
    } else {
        int p = gid - E1 / 4;
        int4 s = ((const int4*)src2)[p];
        int4 d = ((const int4*)dst2)[p];
        int a0 = atomicAdd(&deg2[d.x], 1);
        int a1 = atomicAdd(&deg2[d.y], 1);
        int a2 = atomicAdd(&deg2[d.z], 1);
        int a3 = atomicAdd(&deg2[d.w], 1);
        if (a0 < S2) ell2[d.x * S2 + a0] = s.x;
        if (a1 < S2) ell2[d.y * S2 + a1] = s.y;
        if (a2 < S2) ell2[d.z * S2 + a2] = s.z;
        if (a3 < S2) ell2[d.w * S2 + a3] = s.w;
    }
}

// ---------------------------------------------------------------------------
// Fused layer-1: mean-aggregation (gather) + GEMM in one kernel.
// Block = 32 dst rows. Wave w owns rows w*8..w*8+7 as 4 PAIRS.
// Gather is DOUBLE-BUFFERED: batch k+1's 16 row-loads (+int4 index loads) are
// issued BEFORE batch k is consumed -> batches overlap instead of serializing
// on a full vmcnt drain each ~800ns round trip.
// Masked slots (e+j >= n) select row 0 BEFORE the load (L1-hot, no stale-ELL
// random fetches). Then bf16 MFMA: h = relu([agg|x] . [W1l;W1r] + b1l).
// mfma_f32_16x16x32_bf16: A[m=lane&15][k=quad*8+j]; D: col=lane&15, row=quad*4+reg.
// ---------------------------------------------------------------------------
__global__ __launch_bounds__(256) void agg_gemm1_kernel(
    const float* __restrict__ x, const int* __restrict__ ell1,
    const int* __restrict__ deg1,
    const unsigned short* __restrict__ packedW, const float* __restrict__ b1l,
    float* __restrict__ h) {
    __shared__ short As[32 * LDSTR];   // 14,848 B
    int tid = threadIdx.x;
    int i0 = blockIdx.x * 32;
    int lane = tid & 63;
    int w = tid >> 6;

    // stage x_self -> k[100..199]
    const float2* xs2 = (const float2*)(x + (size_t)i0 * IN_C);
    for (int idx = tid; idx < 32 * 50; idx += 256) {
        int r = idx / 50;
        int p = idx - r * 50;
        float2 v = xs2[idx];
        short2 o = {(short)f2bf(v.x), (short)f2bf(v.y)};
        *(short2*)(As + r * LDSTR + 100 + 2 * p) = o;
    }
    // zero pad k[200..223]
    for (int idx = tid; idx < 32 * 12; idx += 256) {
        int r = idx / 12;
        int p = idx - r * 12;
        short2 z = {0, 0};
        *(short2*)(As + r * LDSTR + 200 + 2 * p) = z;
    }

    // aggregation: 4 row-pairs per wave; ping-pong double-buffered batches
    int l2 = (lane < 50) ? lane : 49;
    #pragma unroll 1
    for (int pr = 0; pr < 4; ++pr) {
        int dA = i0 + w * 8 + pr * 2;
        int dB = dA + 1;
        int ndA = deg1[dA], ndB = deg1[dB];
        int nA = (ndA < S1) ? ndA : S1;
        int nB = (ndB < S1) ? ndB : S1;
        const int* rpA = ell1 + dA * S1;
        const int* rpB = ell1 + dB * S1;
        float Ax0 = 0.f, Ay0 = 0.f, Ax1 = 0.f, Ay1 = 0.f;
        float Bx0 = 0.f, By0 = 0.f, Bx1 = 0.f, By1 = 0.f;
        int nmax = (nA > nB) ? nA : nB;

        float2 pa[8], pb[8], qa[8], qb[8];   // ping (p*) / pong (q*) buffers

        // LOADB: issue 16 row gathers for batch at EE into (VA,VB).
        // Masked slots select row 0 *before* the load (no stale-ELL fetch).
        #define LOADB(VA, VB, EE) do {                                        \
            int4 ia0 = *(const int4*)(rpA + (EE));                            \
            int4 ia1 = *(const int4*)(rpA + (EE) + 4);                        \
            int4 ib0 = *(const int4*)(rpB + (EE));                            \
            int4 ib1 = *(const int4*)(rpB + (EE) + 4);                        \
            int sa[8] = {ia0.x, ia0.y, ia0.z, ia0.w, ia1.x, ia1.y, ia1.z, ia1.w}; \
            int sb[8] = {ib0.x, ib0.y, ib0.z, ib0.w, ib1.x, ib1.y, ib1.z, ib1.w}; \
            _Pragma("unroll")                                                 \
            for (int j = 0; j < 8; ++j) {                                     \
                int sA = ((EE) + j < nA) ? sa[j] : 0;                         \
                int sB = ((EE) + j < nB) ? sb[j] : 0;                         \
                sA = ((unsigned)sA >= (unsigned)N0) ? 0 : sA;                 \
                sB = ((unsigned)sB >= (unsigned)N0) ? 0 : sB;                 \
                VA[j] = ((const float2*)(x + (size_t)sA * IN_C))[l2];         \
                VB[j] = ((const float2*)(x + (size_t)sB * IN_C))[l2];         \
            }                                                                 \
        } while (0)

        #define CONSUME(VA, VB, EE) do {                                      \
            _Pragma("unroll")                                                 \
            for (int j = 0; j < 8; ++j) {                                     \
                float mA = ((EE) + j < nA) ? 1.f : 0.f;                       \
                float mB = ((EE) + j < nB) ? 1.f : 0.f;                       \
                if (j & 1) {                                                  \
                    Ax1 += VA[j].x * mA; Ay1 += VA[j].y * mA;                 \
                    Bx1 += VB[j].x * mB; By1 += VB[j].y * mB;                 \
                } else {                                                      \
                    Ax0 += VA[j].x * mA; Ay0 += VA[j].y * mA;                 \
                    Bx0 += VB[j].x * mB; By0 += VB[j].y * mB;                 \
                }                                                             \
            }                                                                 \
        } while (0)

        LOADB(pa, pb, 0);
        int e = 0;
        for (;;) {
            if (e + 8 < nmax) LOADB(qa, qb, e + 8);   // prefetch next batch
            CONSUME(pa, pb, e);
            e += 8;
            if (e >= nmax) break;
            if (e + 8 < nmax) LOADB(pa, pb, e + 8);
            CONSUME(qa, qb, e);
            e += 8;
            if (e >= nmax) break;
        }
        #undef LOADB
        #undef CONSUME

        float invA = 1.0f / (float)(ndA > 0 ? ndA : 1);
        float invB = 1.0f / (float)(ndB > 0 ? ndB : 1);
        if (lane < 50) {
            short2 oA = {(short)f2bf((Ax0 + Ax1) * invA), (short)f2bf((Ay0 + Ay1) * invA)};
            *(short2*)(As + (w * 8 + pr * 2) * LDSTR + 2 * lane) = oA;
            short2 oB = {(short)f2bf((Bx0 + Bx1) * invB), (short)f2bf((By0 + By1) * invB)};
            *(short2*)(As + (w * 8 + pr * 2 + 1) * LDSTR + 2 * lane) = oB;
        }
    }
    __syncthreads();

    int quad = lane >> 4;
    int m = lane & 15;

    float4v acc[2][4];
    #pragma unroll
    for (int rt = 0; rt < 2; ++rt)
        #pragma unroll
        for (int c = 0; c < 4; ++c) acc[rt][c] = (float4v){0.f, 0.f, 0.f, 0.f};

    #pragma unroll
    for (int ks = 0; ks < KSTEPS; ++ks) {
        int ko = ks * 32 + quad * 8;
        short8 a0 = *(const short8*)(As + (0 * 16 + m) * LDSTR + ko);
        short8 a1 = *(const short8*)(As + (1 * 16 + m) * LDSTR + ko);
        #pragma unroll
        for (int c = 0; c < 4; ++c) {
            int nt = w * 4 + c;
            short8 b = *(const short8*)(packedW + (size_t)(nt * 7 + ks) * 512 + lane * 8);
            acc[0][c] = __builtin_amdgcn_mfma_f32_16x16x32_bf16(a0, b, acc[0][c], 0, 0, 0);
            acc[1][c] = __builtin_amdgcn_mfma_f32_16x16x32_bf16(a1, b, acc[1][c], 0, 0, 0);
        }
    }

    // epilogue: bias + relu, D layout col=lane&15 row=quad*4+reg
    #pragma unroll
    for (int c = 0; c < 4; ++c) {
        int col = (w * 4 + c) * 16 + m;
        float bv = b1l[col];
        #pragma unroll
        for (int rt = 0; rt < 2; ++rt) {
            int rbase = i0 + rt * 16 + quad * 4;
            #pragma unroll
            for (int reg = 0; reg < 4; ++reg) {
                float v = acc[rt][c][reg] + bv;
                h[(size_t)(rbase + reg) * HID + col] = fmaxf(v, 0.f);
            }
        }
    }
}

// ---------------------------------------------------------------------------
// Fused layer 2: per-wave aggregation (float4/lane over 256ch) -> LDS ->
// GEMM (lanes 0..46 = output cols) + bias + wave-level log_softmax.
// ---------------------------------------------------------------------------
__global__ __launch_bounds__(256) void l2_fused_kernel(
    const float* __restrict__ h, const int* __restrict__ ell2,
    const int* __restrict__ deg2,
    const float* __restrict__ W2l, const float* __restrict__ b2l,
    const float* __restrict__ W2r, float* __restrict__ out) {
    __shared__ float sa[4][HID];
    __shared__ float sh_[4][HID];
    int w = threadIdx.x >> 6;
    int lane = threadIdx.x & 63;
    int row = (blockIdx.x << 2) + w;

    int nd = deg2[row];
    int n = (nd < S2) ? nd : S2;
    const int* rp = ell2 + row * S2;
    float4 acc4 = {0.f, 0.f, 0.f, 0.f};
    int e = 0;
    for (; e + 1 < n; e += 2) {
        int s0 = rp[e], s1 = rp[e + 1];
        float4 v0 = ((const float4*)(h + s0 * HID))[lane];
        float4 v1 = ((const float4*)(h + s1 * HID))[lane];
        acc4.x += v0.x + v1.x; acc4.y += v0.y + v1.y;
        acc4.z += v0.z + v1.z; acc4.w += v0.w + v1.w;
    }
    if (e < n) {
        int s0 = rp[e];
        float4 v0 = ((const float4*)(h + s0 * HID))[lane];
        acc4.x += v0.x; acc4.y += v0.y; acc4.z += v0.z; acc4.w += v0.w;
    }
    float inv = 1.0f / (float)(nd > 0 ? nd : 1);
    float4 am = {acc4.x * inv, acc4.y * inv, acc4.z * inv, acc4.w * inv};
    ((float4*)&sa[w][0])[lane] = am;
    ((float4*)&sh_[w][0])[lane] = ((const float4*)(h + row * HID))[lane];
    __syncthreads();

    int j = lane;
    int jj = (j < OUT_C) ? j : (OUT_C - 1);
    float acc = 0.f;
    for (int k = 0; k < HID; k += 4) {
        float4 av = *(const float4*)&sa[w][k];   // same-addr broadcast
        float4 hv = *(const float4*)&sh_[w][k];
        acc += av.x * W2l[(k + 0) * OUT_C + jj] + hv.x * W2r[(k + 0) * OUT_C + jj];
        acc += av.y * W2l[(k + 1) * OUT_C + jj] + hv.y * W2r[(k + 1) * OUT_C + jj];
        acc += av.z * W2l[(k + 2) * OUT_C + jj] + hv.z * W2r[(k + 2) * OUT_C + jj];
        acc += av.w * W2l[(k + 3) * OUT_C + jj] + hv.w * W2r[(k + 3) * OUT_C + jj];
    }
    float v = acc + b2l[jj];
    float vm = (j < OUT_C) ? v : -__builtin_huge_valf();
    #pragma unroll
    for (int s = 32; s > 0; s >>= 1) vm = fmaxf(vm, __shfl_xor(vm, s));
    float ex = (j < OUT_C) ? __expf(v - vm) : 0.f;
    #pragma unroll
    for (int s = 32; s > 0; s >>= 1) ex += __shfl_xor(ex, s);
    if (j < OUT_C) out[row * OUT_C + j] = v - vm - __logf(ex);
}

// ---------------------------------------------------------------------------
extern "C" void kernel_launch(void* const* d_in, const int* in_sizes, int n_in,
                              void* d_out, int out_size, void* d_ws, size_t ws_size,
                              hipStream_t stream) {
    const float* x   = (const float*)d_in[0];
    const float* W1l = (const float*)d_in[1];
    const float* b1l = (const float*)d_in[2];
    const float* W1r = (const float*)d_in[3];
    const float* W2l = (const float*)d_in[4];
    const float* b2l = (const float*)d_in[5];
    const float* W2r = (const float*)d_in[6];
    const int* src1  = (const int*)d_in[7];
    const int* dst1  = (const int*)d_in[8];
    const int* src2  = (const int*)d_in[9];
    const int* dst2  = (const int*)d_in[10];
    float* out = (float*)d_out;

    char* ws = (char*)d_ws;
    size_t off = 0;
    auto alloc = [&](size_t bytes) {
        off = (off + 255) & ~(size_t)255;
        void* p = ws + off;
        off += bytes;
        return p;
    };

    int* deg1 = (int*)alloc(N1 * sizeof(int));       // contiguous with deg2
    int* deg2 = (int*)alloc(N2 * sizeof(int));
    int* ell1 = (int*)alloc((size_t)N1 * S1 * sizeof(int));
    int* ell2 = (int*)alloc((size_t)N2 * S2 * sizeof(int));
    float* h     = (float*)alloc((size_t)N1 * HID * sizeof(float));
    unsigned short* packedW = (unsigned short*)alloc((size_t)16 * 7 * 512 * sizeof(unsigned short));

    hipMemsetAsync(deg1, 0, (N1 + N2) * sizeof(int), stream);

    build_kernel<<<EDGE_BLKS + PACK_BLKS, 256, 0, stream>>>(
        src1, dst1, src2, dst2, deg1, ell1, deg2, ell2, W1l, W1r, packedW);
    agg_gemm1_kernel<<<N1 / 32, 256, 0, stream>>>(x, ell1, deg1, packedW, b1l, h);
    l2_fused_kernel<<<N2 / 4, 256, 0, stream>>>(h, ell2, deg2, W2l, b2l, W2r, out);
}